// Round 3
// baseline (23654.895 us; speedup 1.0000x reference)
//
#include <hip/hip_runtime.h>

typedef unsigned short ushort_t;
typedef unsigned int   uint32;
typedef __attribute__((ext_vector_type(8))) short short8;   // 8 x bf16 (4 VGPRs)
typedef __attribute__((ext_vector_type(4))) float floatx4;  // MFMA 16x16 accum

#define B_    32
#define T_    512
#define H_    1024
#define G4_   4096
#define HSEQ_ (B_*T_*H_)     // 16777216

// ---- workspace layout (bytes) — total 128 KB + 256 B ----
#define H0_OFF  0ul          // bf16 [32][1024] = 65536 B
#define H1_OFF  65536ul      // bf16 [32][1024] = 65536 B
#define CTR_OFF 131072ul     // uint32 barrier counter

#define NBLK 64

__device__ __forceinline__ ushort_t f2b_rne(float f) {
    uint32 u = __float_as_uint(f);
    u += 0x7fffu + ((u >> 16) & 1u);      // round-to-nearest-even
    return (ushort_t)(u >> 16);
}
__device__ __forceinline__ float sigm(float x)  { return 1.f / (1.f + __expf(-x)); }
__device__ __forceinline__ float tanh_(float x) { return 1.f - 2.f / (__expf(2.f * x) + 1.f); }

// Load 8 consecutive fp32 and truncate-pack to 8 bf16 (v_perm_b32, 4 ops).
// Truncation (round-toward-zero) bias ~0.2% — far inside the 3% tolerance.
__device__ __forceinline__ short8 ld_f32x8_trunc(const float* p) {
    union { uint32 u[8]; } s;
    const uint4 lo = *(const uint4*)(p);
    const uint4 hi = *(const uint4*)(p + 4);
    union { uint32 u[4]; short8 v; } r;
    // perm(S0,S1,0x07060302): dst = (S0_hi16 << 16) | S1_hi16 -> lane0=S1, lane1=S0
    r.u[0] = __builtin_amdgcn_perm(lo.y, lo.x, 0x07060302u);
    r.u[1] = __builtin_amdgcn_perm(lo.w, lo.z, 0x07060302u);
    r.u[2] = __builtin_amdgcn_perm(hi.y, hi.x, 0x07060302u);
    r.u[3] = __builtin_amdgcn_perm(hi.w, hi.z, 0x07060302u);
    return r.v;
}

// ---------------------------------------------------------------------------
// Persistent LSTM scan, fully fused, fp32 I/O + bf16 MFMA compute.
// 64 blocks x 256 thr (4 waves). Block b owns hidden units [16b,16b+16).
// Wave w computes gate w (i/f/g/o) for those units: 32x16 tile, two K=1024
// GEMMs per step (x_t @ W_ih + h_t @ W_hh) into one fp32 accumulator.
// Both weight fragment sets register-resident (2 x 128 VGPRs, RNE-converted
// once). h ping-pongs as bf16 in ws; fp32 c-state lives in registers for the
// whole scan; one device-scope barrier per timestep (skipped on the last).
// ---------------------------------------------------------------------------
__launch_bounds__(256, 1)
__global__ void lstm_scan(const float* __restrict__ x,     // [32][512][1024] f32
                          const float* __restrict__ wih,   // [1024][4096] f32 row-major
                          const float* __restrict__ whh,   // [1024][4096] f32 row-major
                          const float* __restrict__ bias,  // [4096] f32
                          ushort_t* __restrict__ h0buf,    // bf16 ping
                          ushort_t* __restrict__ h1buf,    // bf16 pong
                          float* __restrict__ out,         // f32: hseq | h_T | c_T
                          uint32* __restrict__ ctr)
{
    const int tid  = threadIdx.x;
    const int bid  = blockIdx.x;
    const int wave = tid >> 6, lane = tid & 63, l16 = lane & 15, quad = lane >> 4;
    const int unit0 = bid * 16;
    const int col0  = wave * 1024 + unit0;    // this wave's 16 gate-columns in 4H

    __shared__ float gates[4 * 32 * 17];      // [gate][batch m][unit jj], pad 17

    // --- one-time: B-fragments (RNE fp32->bf16) from row-major weights ---
    // B-frag (16x16x32): lane holds B[k][n], n = l16, k = quad*8 + j.
    short8 wif[32], whf[32];
    {
        const float* pih = wih + (size_t)(quad * 8) * G4_ + col0 + l16;
        const float* phh = whh + (size_t)(quad * 8) * G4_ + col0 + l16;
#pragma unroll
        for (int kk = 0; kk < 32; kk++) {
            short8 vi, vh;
#pragma unroll
            for (int j = 0; j < 8; j++) {
                vi[j] = (short)f2b_rne(pih[(size_t)(kk * 32 + j) * G4_]);
                vh[j] = (short)f2b_rne(phh[(size_t)(kk * 32 + j) * G4_]);
            }
            wif[kk] = vi;
            whf[kk] = vh;
        }
    }

    // --- bias preload for elementwise phase: pairs p=tid, tid+256 ---
    const int jj0 = tid & 15;
    float bia[4];
#pragma unroll
    for (int g = 0; g < 4; g++) bia[g] = bias[g * 1024 + unit0 + jj0];

    float cst[2] = {0.f, 0.f};   // fp32 c-state, pair p -> (b=p>>4, jj=p&15)

    for (int t = 0; t < 512; t++) {
        const ushort_t* hr = (t & 1) ? h1buf : h0buf;   // read h_t (bf16)
        ushort_t*       hw = (t & 1) ? h0buf : h1buf;   // write h_{t+1}

        floatx4 a0a = (floatx4){0.f, 0.f, 0.f, 0.f};
        floatx4 a0b = a0a, a1a = a0a, a1b = a0a;

        // --- GEMM 1: x_t @ W_ih  (A rows = batch; fp32 load + trunc pack) ---
        {
            const float* xp0 = x + ((size_t)l16 * T_ + t) * H_ + quad * 8;
            const float* xp1 = x + ((size_t)(16 + l16) * T_ + t) * H_ + quad * 8;
#pragma unroll
            for (int kk = 0; kk < 32; kk++) {
                const short8 a0 = ld_f32x8_trunc(xp0 + kk * 32);
                const short8 a1 = ld_f32x8_trunc(xp1 + kk * 32);
                if (kk & 1) {
                    a0b = __builtin_amdgcn_mfma_f32_16x16x32_bf16(a0, wif[kk], a0b, 0, 0, 0);
                    a1b = __builtin_amdgcn_mfma_f32_16x16x32_bf16(a1, wif[kk], a1b, 0, 0, 0);
                } else {
                    a0a = __builtin_amdgcn_mfma_f32_16x16x32_bf16(a0, wif[kk], a0a, 0, 0, 0);
                    a1a = __builtin_amdgcn_mfma_f32_16x16x32_bf16(a1, wif[kk], a1a, 0, 0, 0);
                }
            }
        }
        // --- GEMM 2: h_t @ W_hh  (A from bf16 ping-pong, same accumulators) ---
        {
            const ushort_t* hp0 = hr + l16 * H_ + quad * 8;
            const ushort_t* hp1 = hr + (16 + l16) * H_ + quad * 8;
#pragma unroll
            for (int kk = 0; kk < 32; kk++) {
                const short8 a0 = *(const short8*)(hp0 + kk * 32);
                const short8 a1 = *(const short8*)(hp1 + kk * 32);
                if (kk & 1) {
                    a0b = __builtin_amdgcn_mfma_f32_16x16x32_bf16(a0, whf[kk], a0b, 0, 0, 0);
                    a1b = __builtin_amdgcn_mfma_f32_16x16x32_bf16(a1, whf[kk], a1b, 0, 0, 0);
                } else {
                    a0a = __builtin_amdgcn_mfma_f32_16x16x32_bf16(a0, whf[kk], a0a, 0, 0, 0);
                    a1a = __builtin_amdgcn_mfma_f32_16x16x32_bf16(a1, whf[kk], a1a, 0, 0, 0);
                }
            }
        }
        const floatx4 acc0 = a0a + a0b;   // batch rows quad*4+r
        const floatx4 acc1 = a1a + a1b;   // batch rows 16+quad*4+r

        // C/D layout: col = lane&15 (unit), row = quad*4 + reg (batch)
#pragma unroll
        for (int rr = 0; rr < 4; rr++) {
            gates[(wave * 32 + quad * 4 + rr) * 17 + l16]      = acc0[rr];
            gates[(wave * 32 + 16 + quad * 4 + rr) * 17 + l16] = acc1[rr];
        }
        __syncthreads();

        // --- elementwise gate math + state update (fp32) ---
#pragma unroll
        for (int pi = 0; pi < 2; pi++) {
            const int p = tid + pi * 256;
            const int b = p >> 4, jj = p & 15;
            const float gi = gates[(0 * 32 + b) * 17 + jj] + bia[0];
            const float gf = gates[(1 * 32 + b) * 17 + jj] + bia[1];
            const float gg = gates[(2 * 32 + b) * 17 + jj] + bia[2];
            const float go = gates[(3 * 32 + b) * 17 + jj] + bia[3];
            const float iv = sigm(gi);
            const float fv = sigm(gf);
            const float gv = tanh_(gg);
            const float ov = sigm(go);
            const float c = fv * cst[pi] + iv * gv;
            cst[pi] = c;
            const float h = ov * tanh_(c);
            hw[b * H_ + unit0 + jj] = f2b_rne(h);                  // next-step h (bf16)
            out[(size_t)(b * T_ + t) * H_ + unit0 + jj] = h;       // hidden_seq (f32)
            if (t == 511) {
                out[HSEQ_ + b * H_ + unit0 + jj] = h;              // h_T
                out[HSEQ_ + B_ * H_ + b * H_ + unit0 + jj] = c;    // c_T
            }
        }

        // --- device-scope grid barrier (skip after the last step) ---
        __syncthreads();
        if (t != 511) {
            if (tid == 0) {
                __threadfence();   // release: flush this block's h writes
                __hip_atomic_fetch_add(ctr, 1u, __ATOMIC_RELAXED, __HIP_MEMORY_SCOPE_AGENT);
                const uint32 target = (uint32)NBLK * (uint32)(t + 1);
                while (__hip_atomic_load(ctr, __ATOMIC_RELAXED, __HIP_MEMORY_SCOPE_AGENT) < target) {
                    __builtin_amdgcn_s_sleep(1);
                }
                __threadfence();   // acquire: see other blocks' h writes
            }
            __syncthreads();
        }
    }
}

// ---------------------------------------------------------------------------
extern "C" void kernel_launch(void* const* d_in, const int* in_sizes, int n_in,
                              void* d_out, int out_size, void* d_ws, size_t ws_size,
                              hipStream_t stream)
{
    const float* x    = (const float*)d_in[0];  // [32,512,1024] f32
    const float* wih  = (const float*)d_in[1];  // [1024,4096] f32
    const float* whh  = (const float*)d_in[2];  // [1024,4096] f32
    const float* bias = (const float*)d_in[3];  // [4096] f32
    float* out = (float*)d_out;
    char* ws = (char*)d_ws;

    ushort_t* h0  = (ushort_t*)(ws + H0_OFF);
    ushort_t* h1  = (ushort_t*)(ws + H1_OFF);
    uint32*   ctr = (uint32*)(ws + CTR_OFF);

    // zero h ping-pong buffers + barrier counter (ws is poisoned 0xAA each run)
    hipMemsetAsync(ws, 0, 131072 + 256, stream);

    hipLaunchKernelGGL(lstm_scan, dim3(NBLK), dim3(256), 0, stream,
                       x, wih, whh, bias, h0, h1, out, ctr);
}

// Round 4
// 6322.973 us; speedup vs baseline: 3.7411x; 3.7411x over previous
//
#include <hip/hip_runtime.h>

typedef unsigned short ushort_t;
typedef unsigned int   uint32;
typedef __attribute__((ext_vector_type(8))) short short8;   // 8 x bf16 (4 VGPRs)
typedef __attribute__((ext_vector_type(4))) float floatx4;  // MFMA 16x16 accum

#define B_    32
#define T_    512
#define H_    1024
#define G4_   4096
#define HSEQ_ (B_*T_*H_)     // 16777216

// ---- workspace layout (bytes) — total 128 KB + 256 B ----
// h buffers are stored in MFMA A-fragment order: elem (b,k) at
// (k/32)*1024 + b*32 + (k%32)   [bf16 elements; 2 KB per 32-k block]
#define H0_OFF  0ul
#define H1_OFF  65536ul
#define CTR_OFF 131072ul

#define NBLK 64

__device__ __forceinline__ ushort_t f2b_rne(float f) {
    uint32 u = __float_as_uint(f);
    u += 0x7fffu + ((u >> 16) & 1u);      // round-to-nearest-even
    return (ushort_t)(u >> 16);
}
__device__ __forceinline__ float sigm(float x)  { return 1.f / (1.f + __expf(-x)); }
__device__ __forceinline__ float tanh_(float x) { return 1.f - 2.f / (__expf(2.f * x) + 1.f); }

// ---------------------------------------------------------------------------
// Persistent LSTM scan v2. 64 blocks x 512 thr (8 waves).
// Block b owns hidden units [16b,16b+16). Wave w: gate g=w&3, K-half kh=w>>2.
// Per wave: 16 B-frags of W_ih + 16 of W_hh register-resident (128 VGPRs —
// half of R3's 256, which capped the v-file and caused hot-loop spills).
// Per step: h-GEMM (A-frags coalesced from fragment-layout global h buffer)
// -> gates via 2 LDS buffers (K-half reduction) -> elementwise -> barrier
// arrive -> x(t+1) staged to LDS + x-GEMM in the barrier shadow -> spin.
// ---------------------------------------------------------------------------
__launch_bounds__(512, 2)
__global__ void lstm_scan(const float* __restrict__ x,     // [32][512][1024] f32
                          const float* __restrict__ wih,   // [1024][4096] f32
                          const float* __restrict__ whh,   // [1024][4096] f32
                          const float* __restrict__ bias,  // [4096] f32
                          ushort_t* __restrict__ h0buf,    // bf16 frag-layout ping
                          ushort_t* __restrict__ h1buf,    // bf16 frag-layout pong
                          float* __restrict__ out,         // f32: hseq | h_T | c_T
                          uint32* __restrict__ ctr)
{
    const int tid  = threadIdx.x;
    const int bid  = blockIdx.x;
    const int wave = tid >> 6, lane = tid & 63, l16 = lane & 15, quad = lane >> 4;
    const int g     = wave & 3;          // gate 0..3 (i,f,g,o)
    const int khalf = wave >> 2;         // K-half 0/1
    const int unit0 = bid * 16;
    const int col0  = g * 1024 + unit0 + l16;   // this lane's gate-column
    const int kbase = khalf * 512;

    __shared__ ushort_t xs[32 * 1024];   // 64 KB: x_t bf16, fragment layout
    __shared__ float gA[4 * 32 * 17];    // gates partial, K-half 0 (+bias)
    __shared__ float gB[4 * 32 * 17];    // gates partial, K-half 1

    // --- one-time: register-resident B-frags (RNE fp32->bf16) ---
    // B-frag: lane holds B[k][n], n = col0, k = kbase + kk*32 + quad*8 + j
    short8 wif[16], whf[16];
#pragma unroll
    for (int kk = 0; kk < 16; kk++) {
        short8 vi, vh;
#pragma unroll
        for (int j = 0; j < 8; j++) {
            const size_t k = (size_t)(kbase + kk * 32 + quad * 8 + j);
            vi[j] = (short)f2b_rne(wih[k * G4_ + col0]);
            vh[j] = (short)f2b_rne(whh[k * G4_ + col0]);
        }
        wif[kk] = vi;
        whf[kk] = vh;
    }
    const float bcol = (khalf == 0) ? bias[col0] : 0.f;  // bias folded into acc init

    // elementwise ownership: thread tid -> (batch eb, unit-offset ej)
    const int eb = tid >> 4, ej = tid & 15;
    const int hwoff = (bid >> 1) * 1024 + eb * 32 + 16 * (bid & 1) + ej; // frag-layout
    float cst = 0.f;

    floatx4 a0a, a0b, a1a, a1b;

    // ---- prologue: stage x(0) + x-GEMM(0) ----
    {
        const int sb = tid >> 4, sc = tid & 15;          // batch row, 64-elem chunk
        const float* xrow = x + ((size_t)sb * T_ + 0) * H_ + sc * 64;
#pragma unroll
        for (int q = 0; q < 8; q++) {
            const uint4 u0 = *(const uint4*)(xrow + q * 8);
            const uint4 u1 = *(const uint4*)(xrow + q * 8 + 4);
            uint4 p;
            p.x = __builtin_amdgcn_perm(u0.y, u0.x, 0x07060302u);
            p.y = __builtin_amdgcn_perm(u0.w, u0.z, 0x07060302u);
            p.z = __builtin_amdgcn_perm(u1.y, u1.x, 0x07060302u);
            p.w = __builtin_amdgcn_perm(u1.w, u1.z, 0x07060302u);
            const int k = sc * 64 + q * 8;
            *(uint4*)&xs[(k >> 5) * 1024 + sb * 32 + (k & 31)] = p;
        }
    }
    __syncthreads();
    a0a = (floatx4){bcol, bcol, bcol, bcol};
    a1a = a0a;
    a0b = (floatx4){0.f, 0.f, 0.f, 0.f};
    a1b = a0b;
#pragma unroll
    for (int kk = 0; kk < 16; kk++) {
        const ushort_t* ps = &xs[(khalf * 16 + kk) * 1024 + quad * 8];
        const short8 a0 = *(const short8*)(ps + l16 * 32);
        const short8 a1 = *(const short8*)(ps + (16 + l16) * 32);
        if (kk & 1) {
            a0b = __builtin_amdgcn_mfma_f32_16x16x32_bf16(a0, wif[kk], a0b, 0, 0, 0);
            a1b = __builtin_amdgcn_mfma_f32_16x16x32_bf16(a1, wif[kk], a1b, 0, 0, 0);
        } else {
            a0a = __builtin_amdgcn_mfma_f32_16x16x32_bf16(a0, wif[kk], a0a, 0, 0, 0);
            a1a = __builtin_amdgcn_mfma_f32_16x16x32_bf16(a1, wif[kk], a1a, 0, 0, 0);
        }
    }

    for (int t = 0; t < 512; t++) {
        const ushort_t* hr = (t & 1) ? h1buf : h0buf;   // h_t (frag layout)
        ushort_t*       hw = (t & 1) ? h0buf : h1buf;   // h_{t+1}

        // --- h-GEMM: coalesced 16B/lane A-frag loads from global h buffer ---
#pragma unroll
        for (int kk = 0; kk < 16; kk++) {
            const ushort_t* pa = hr + (khalf * 16 + kk) * 1024 + quad * 8;
            const short8 a0 = *(const short8*)(pa + l16 * 32);
            const short8 a1 = *(const short8*)(pa + (16 + l16) * 32);
            if (kk & 1) {
                a0b = __builtin_amdgcn_mfma_f32_16x16x32_bf16(a0, whf[kk], a0b, 0, 0, 0);
                a1b = __builtin_amdgcn_mfma_f32_16x16x32_bf16(a1, whf[kk], a1b, 0, 0, 0);
            } else {
                a0a = __builtin_amdgcn_mfma_f32_16x16x32_bf16(a0, whf[kk], a0a, 0, 0, 0);
                a1a = __builtin_amdgcn_mfma_f32_16x16x32_bf16(a1, whf[kk], a1a, 0, 0, 0);
            }
        }
        const floatx4 s0 = a0a + a0b;   // batch rows quad*4+rr
        const floatx4 s1 = a1a + a1b;   // batch rows 16+quad*4+rr
        float* gd = khalf ? gB : gA;
#pragma unroll
        for (int rr = 0; rr < 4; rr++) {
            gd[(g * 32 + quad * 4 + rr) * 17 + l16]      = s0[rr];
            gd[(g * 32 + 16 + quad * 4 + rr) * 17 + l16] = s1[rr];
        }
        __syncthreads();

        // --- elementwise: 512 threads, one (b,unit) pair each ---
        {
            const float gi = gA[(0 * 32 + eb) * 17 + ej] + gB[(0 * 32 + eb) * 17 + ej];
            const float gf = gA[(1 * 32 + eb) * 17 + ej] + gB[(1 * 32 + eb) * 17 + ej];
            const float gg = gA[(2 * 32 + eb) * 17 + ej] + gB[(2 * 32 + eb) * 17 + ej];
            const float go = gA[(3 * 32 + eb) * 17 + ej] + gB[(3 * 32 + eb) * 17 + ej];
            const float iv = sigm(gi);
            const float fv = sigm(gf);
            const float gv = tanh_(gg);
            const float ov = sigm(go);
            const float c = fv * cst + iv * gv;
            cst = c;
            const float h = ov * tanh_(c);
            hw[hwoff] = f2b_rne(h);                              // frag-layout h
            out[((size_t)eb * T_ + t) * H_ + unit0 + ej] = h;    // hidden_seq
            if (t == 511) {
                out[HSEQ_ + eb * H_ + unit0 + ej] = h;           // h_T
                out[HSEQ_ + B_ * H_ + eb * H_ + unit0 + ej] = cst; // c_T
            }
        }
        // drain every wave's h/out writes (syncthreads emits vmcnt(0)) before release
        __syncthreads();

        if (t < 511) {
            // --- barrier ARRIVE (release): h writes are drained; flush L2 ---
            if (tid == 0) {
                __threadfence();
                __hip_atomic_fetch_add(ctr, 1u, __ATOMIC_RELAXED, __HIP_MEMORY_SCOPE_AGENT);
            }
            // --- barrier shadow: stage x(t+1) + x-GEMM(t+1) ---
            {
                const int sb = tid >> 4, sc = tid & 15;
                const float* xrow = x + ((size_t)sb * T_ + (t + 1)) * H_ + sc * 64;
#pragma unroll
                for (int q = 0; q < 8; q++) {
                    const uint4 u0 = *(const uint4*)(xrow + q * 8);
                    const uint4 u1 = *(const uint4*)(xrow + q * 8 + 4);
                    uint4 p;
                    p.x = __builtin_amdgcn_perm(u0.y, u0.x, 0x07060302u);
                    p.y = __builtin_amdgcn_perm(u0.w, u0.z, 0x07060302u);
                    p.z = __builtin_amdgcn_perm(u1.y, u1.x, 0x07060302u);
                    p.w = __builtin_amdgcn_perm(u1.w, u1.z, 0x07060302u);
                    const int k = sc * 64 + q * 8;
                    *(uint4*)&xs[(k >> 5) * 1024 + sb * 32 + (k & 31)] = p;
                }
            }
            __syncthreads();
            a0a = (floatx4){bcol, bcol, bcol, bcol};
            a1a = a0a;
            a0b = (floatx4){0.f, 0.f, 0.f, 0.f};
            a1b = a0b;
#pragma unroll
            for (int kk = 0; kk < 16; kk++) {
                const ushort_t* ps = &xs[(khalf * 16 + kk) * 1024 + quad * 8];
                const short8 a0 = *(const short8*)(ps + l16 * 32);
                const short8 a1 = *(const short8*)(ps + (16 + l16) * 32);
                if (kk & 1) {
                    a0b = __builtin_amdgcn_mfma_f32_16x16x32_bf16(a0, wif[kk], a0b, 0, 0, 0);
                    a1b = __builtin_amdgcn_mfma_f32_16x16x32_bf16(a1, wif[kk], a1b, 0, 0, 0);
                } else {
                    a0a = __builtin_amdgcn_mfma_f32_16x16x32_bf16(a0, wif[kk], a0a, 0, 0, 0);
                    a1a = __builtin_amdgcn_mfma_f32_16x16x32_bf16(a1, wif[kk], a1a, 0, 0, 0);
                }
            }
            // --- barrier WAIT (acquire) ---
            if (tid == 0) {
                const uint32 target = (uint32)NBLK * (uint32)(t + 1);
                while (__hip_atomic_load(ctr, __ATOMIC_RELAXED, __HIP_MEMORY_SCOPE_AGENT) < target) {
                    __builtin_amdgcn_s_sleep(1);
                }
                __threadfence();   // acquire: invalidate caches, see others' h
            }
            __syncthreads();
        }
    }
}

// ---------------------------------------------------------------------------
extern "C" void kernel_launch(void* const* d_in, const int* in_sizes, int n_in,
                              void* d_out, int out_size, void* d_ws, size_t ws_size,
                              hipStream_t stream)
{
    const float* x    = (const float*)d_in[0];  // [32,512,1024] f32
    const float* wih  = (const float*)d_in[1];  // [1024,4096] f32
    const float* whh  = (const float*)d_in[2];  // [1024,4096] f32
    const float* bias = (const float*)d_in[3];  // [4096] f32
    float* out = (float*)d_out;
    char* ws = (char*)d_ws;

    ushort_t* h0  = (ushort_t*)(ws + H0_OFF);
    ushort_t* h1  = (ushort_t*)(ws + H1_OFF);
    uint32*   ctr = (uint32*)(ws + CTR_OFF);

    // zero h ping-pong buffers + barrier counter (ws is poisoned 0xAA each run)
    hipMemsetAsync(ws, 0, 131072 + 256, stream);

    hipLaunchKernelGGL(lstm_scan, dim3(NBLK), dim3(512), 0, stream,
                       x, wih, whh, bias, h0, h1, out, ctr);
}

// Round 5
// 5878.477 us; speedup vs baseline: 4.0240x; 1.0756x over previous
//
#include <hip/hip_runtime.h>

typedef unsigned short ushort_t;
typedef unsigned int   uint32;
typedef __attribute__((ext_vector_type(8))) short short8;   // 8 x bf16 (4 VGPRs)
typedef __attribute__((ext_vector_type(4))) float floatx4;  // MFMA 16x16 accum

#define B_    32
#define T_    512
#define H_    1024
#define G4_   4096
#define HSEQ_ (B_*T_*H_)     // 16777216

#define NBLK 64

// ---- ws layout, xproj path (requires ws_size >= WS_NEED) ----
#define XPROJ_OFF 0ul                 // bf16 [16384][4096] = 134217728
#define WTIH_OFF  134217728ul         // bf16 [4096][1024]  = 8388608
#define WTHH_OFF  142606336ul         // bf16 [4096][1024]  = 8388608
#define H0X_OFF   150994944ul         // bf16 frag-layout   = 65536
#define H1X_OFF   151060480ul         // bf16 frag-layout   = 65536
#define FLAGS_OFF 151126016ul         // 64 x uint32, 64B-padded = 4096
#define WS_NEED   151130112ul

// ---- ws layout, fallback path (R4) ----
#define H0_OFF  0ul
#define H1_OFF  65536ul
#define CTR_OFF 131072ul

__device__ __forceinline__ ushort_t f2b_rne(float f) {
    uint32 u = __float_as_uint(f);
    u += 0x7fffu + ((u >> 16) & 1u);      // round-to-nearest-even
    return (ushort_t)(u >> 16);
}
__device__ __forceinline__ float b2f(ushort_t u) { return __uint_as_float(((uint32)u) << 16); }
__device__ __forceinline__ float sigm(float x)  { return 1.f / (1.f + __expf(-x)); }
__device__ __forceinline__ float tanh_(float x) { return 1.f - 2.f / (__expf(2.f * x) + 1.f); }

// ---------------------------------------------------------------------------
// Transpose+convert: in fp32 [1024 k][4096 n] -> out bf16 [4096 n][1024 k].
// Lane-consecutive n => strided loads are coalesced across lanes; each thread
// packs 8 k-values into one 16B store. One-time, 24 MB total traffic.
// ---------------------------------------------------------------------------
__global__ void transpose_cvt(const float* __restrict__ in, ushort_t* __restrict__ out)
{
    const int id = blockIdx.x * 256 + threadIdx.x;    // 524288 total
    const int n  = id & 4095;
    const int k0 = (id >> 12) * 8;
    union { ushort_t v[8]; uint4 q; } r;
#pragma unroll
    for (int j = 0; j < 8; j++)
        r.v[j] = f2b_rne(in[(size_t)(k0 + j) * G4_ + n]);
    *(uint4*)(out + (size_t)n * 1024 + k0) = r.q;
}

// ---------------------------------------------------------------------------
// xproj GEMM: xproj[m][n] = bf16( sum_k x[m][k]*W_ih[k][n] + bias[n] )
// A = x fp32 [16384][1024] (cvt on stage), Bt = wt_ih bf16 [4096][1024].
// 128x128 tile, BK=32, 256 thr (2x2 waves of 64x64), 16x16x32 bf16 MFMA.
// ---------------------------------------------------------------------------
__launch_bounds__(256, 2)
__global__ void gemm_xproj(const float* __restrict__ A, const ushort_t* __restrict__ Bt,
                           const float* __restrict__ bias, ushort_t* __restrict__ C)
{
    __shared__ ushort_t As[128 * 32];
    __shared__ ushort_t Bs[128 * 32];
    const int tid = threadIdx.x;
    const int wave = tid >> 6, lane = tid & 63, l16 = lane & 15, quad = lane >> 4;
    const int wm = (wave >> 1) * 64, wn = (wave & 1) * 64;
    const int m0 = blockIdx.y * 128, n0 = blockIdx.x * 128;
    const int r = tid >> 2;               // 0..63 (staging row)
    const int kp = (tid & 3) * 8;         // 0..24 step 8

    floatx4 acc[4][4];
#pragma unroll
    for (int i = 0; i < 4; i++)
#pragma unroll
        for (int j = 0; j < 4; j++) acc[i][j] = (floatx4){0.f, 0.f, 0.f, 0.f};

    for (int kk = 0; kk < 1024; kk += 32) {
        // A: fp32 -> bf16 pack, rows r and r+64
#pragma unroll
        for (int h = 0; h < 2; h++) {
            const float* ap = A + (size_t)(m0 + r + h * 64) * 1024 + kk + kp;
            const uint4 u0 = *(const uint4*)ap;
            const uint4 u1 = *(const uint4*)(ap + 4);
            uint4 p;
            p.x = __builtin_amdgcn_perm(u0.y, u0.x, 0x07060302u);
            p.y = __builtin_amdgcn_perm(u0.w, u0.z, 0x07060302u);
            p.z = __builtin_amdgcn_perm(u1.y, u1.x, 0x07060302u);
            p.w = __builtin_amdgcn_perm(u1.w, u1.z, 0x07060302u);
            *(uint4*)&As[(r + h * 64) * 32 + kp] = p;
        }
        // B: bf16 direct 16B
        const ushort_t* bp = Bt + (size_t)(n0 + r) * 1024 + kk + kp;
        *(uint4*)&Bs[r * 32 + kp]        = *(const uint4*)bp;
        *(uint4*)&Bs[(r + 64) * 32 + kp] = *(const uint4*)(bp + 64 * 1024);
        __syncthreads();

        short8 af[4], bfr[4];
#pragma unroll
        for (int i = 0; i < 4; i++) af[i]  = *(const short8*)&As[(wm + i * 16 + l16) * 32 + quad * 8];
#pragma unroll
        for (int j = 0; j < 4; j++) bfr[j] = *(const short8*)&Bs[(wn + j * 16 + l16) * 32 + quad * 8];
#pragma unroll
        for (int i = 0; i < 4; i++)
#pragma unroll
            for (int j = 0; j < 4; j++)
                acc[i][j] = __builtin_amdgcn_mfma_f32_16x16x32_bf16(af[i], bfr[j], acc[i][j], 0, 0, 0);
        __syncthreads();
    }

    // epilogue: C/D layout col = lane&15, row = quad*4 + reg; fold bias
#pragma unroll
    for (int i = 0; i < 4; i++) {
        const int gm = m0 + wm + i * 16 + quad * 4;
#pragma unroll
        for (int j = 0; j < 4; j++) {
            const int gn = n0 + wn + j * 16 + l16;
            const float bv = bias[gn];
#pragma unroll
            for (int rr = 0; rr < 4; rr++)
                C[(size_t)(gm + rr) * G4_ + gn] = f2b_rne(acc[i][j][rr] + bv);
        }
    }
}

// ---------------------------------------------------------------------------
// Scan v3 (xproj path). 64 blocks x 512 thr (8 waves). Block b owns units
// [16b,16b+16); wave w: gate g=w&3, K-half kh=w>>2 (16 reg-resident W_hh
// B-frags = 64 VGPRs). Per step: prefetch xproj -> h-GEMM (coalesced frag
// loads from global ping-pong) -> LDS K-half reduce -> elementwise ->
// flag-array barrier (parallel arrive, wave-0 ballot poll).
// ---------------------------------------------------------------------------
__launch_bounds__(512, 2)
__global__ void lstm_scan_xp(const ushort_t* __restrict__ xproj, // [16384][4096] bf16
                             const ushort_t* __restrict__ wthh,  // [4096][1024] bf16
                             ushort_t* __restrict__ h0buf,       // bf16 frag-layout
                             ushort_t* __restrict__ h1buf,
                             float* __restrict__ out,            // f32: hseq|h_T|c_T
                             uint32* __restrict__ flags)         // 64, stride 16
{
    const int tid  = threadIdx.x;
    const int bid  = blockIdx.x;
    const int wave = tid >> 6, lane = tid & 63, l16 = lane & 15, quad = lane >> 4;
    const int g     = wave & 3;
    const int khalf = wave >> 2;
    const int unit0 = bid * 16;
    const int col0  = g * 1024 + unit0 + l16;

    __shared__ float gA[4 * 32 * 17];
    __shared__ float gB[4 * 32 * 17];

    // one-time: W_hh B-frags from transposed bf16 weights (16B vector loads)
    short8 whf[16];
#pragma unroll
    for (int kk = 0; kk < 16; kk++)
        whf[kk] = *(const short8*)(wthh + (size_t)col0 * 1024 + khalf * 512 + kk * 32 + quad * 8);

    const int eb = tid >> 4, ej = tid & 15;
    const int hwoff = (bid >> 1) * 1024 + eb * 32 + 16 * (bid & 1) + ej; // frag layout
    float cst = 0.f;

    for (int t = 0; t < 512; t++) {
        const ushort_t* hr = (t & 1) ? h1buf : h0buf;
        ushort_t*       hw = (t & 1) ? h0buf : h1buf;

        // prefetch this thread's 4 xproj gate values (streamed, hidden by GEMM)
        ushort_t xq[4];
        {
            const ushort_t* xp = xproj + ((size_t)eb * T_ + t) * G4_ + unit0 + ej;
#pragma unroll
            for (int gg = 0; gg < 4; gg++) xq[gg] = xp[gg * 1024];
        }

        // h-GEMM: coalesced 16B/lane A-frag loads from global h buffer
        floatx4 a0a = (floatx4){0.f, 0.f, 0.f, 0.f};
        floatx4 a0b = a0a, a1a = a0a, a1b = a0a;
#pragma unroll
        for (int kk = 0; kk < 16; kk++) {
            const ushort_t* pa = hr + (khalf * 16 + kk) * 1024 + quad * 8;
            const short8 a0 = *(const short8*)(pa + l16 * 32);
            const short8 a1 = *(const short8*)(pa + (16 + l16) * 32);
            if (kk & 1) {
                a0b = __builtin_amdgcn_mfma_f32_16x16x32_bf16(a0, whf[kk], a0b, 0, 0, 0);
                a1b = __builtin_amdgcn_mfma_f32_16x16x32_bf16(a1, whf[kk], a1b, 0, 0, 0);
            } else {
                a0a = __builtin_amdgcn_mfma_f32_16x16x32_bf16(a0, whf[kk], a0a, 0, 0, 0);
                a1a = __builtin_amdgcn_mfma_f32_16x16x32_bf16(a1, whf[kk], a1a, 0, 0, 0);
            }
        }
        const floatx4 s0 = a0a + a0b;
        const floatx4 s1 = a1a + a1b;
        float* gd = khalf ? gB : gA;
#pragma unroll
        for (int rr = 0; rr < 4; rr++) {
            gd[(g * 32 + quad * 4 + rr) * 17 + l16]      = s0[rr];
            gd[(g * 32 + 16 + quad * 4 + rr) * 17 + l16] = s1[rr];
        }
        __syncthreads();

        // elementwise: thread -> (batch eb, unit ej)
        {
            const float gi = gA[(0 * 32 + eb) * 17 + ej] + gB[(0 * 32 + eb) * 17 + ej] + b2f(xq[0]);
            const float gf = gA[(1 * 32 + eb) * 17 + ej] + gB[(1 * 32 + eb) * 17 + ej] + b2f(xq[1]);
            const float gg = gA[(2 * 32 + eb) * 17 + ej] + gB[(2 * 32 + eb) * 17 + ej] + b2f(xq[2]);
            const float go = gA[(3 * 32 + eb) * 17 + ej] + gB[(3 * 32 + eb) * 17 + ej] + b2f(xq[3]);
            const float iv = sigm(gi);
            const float fv = sigm(gf);
            const float gv = tanh_(gg);
            const float ov = sigm(go);
            const float c = fv * cst + iv * gv;
            cst = c;
            const float h = ov * tanh_(c);
            hw[hwoff] = f2b_rne(h);
            out[((size_t)eb * T_ + t) * H_ + unit0 + ej] = h;
            if (t == 511) {
                out[HSEQ_ + eb * H_ + unit0 + ej] = h;
                out[HSEQ_ + B_ * H_ + eb * H_ + unit0 + ej] = c;
            }
        }
        __syncthreads();   // drain all waves' h/out writes (vmcnt 0) pre-release

        if (t < 511) {
            // parallel arrive: release fence + per-block flag store
            if (tid == 0) {
                __threadfence();
                __hip_atomic_store(&flags[bid * 16], (uint32)(t + 1),
                                   __ATOMIC_RELAXED, __HIP_MEMORY_SCOPE_AGENT);
            }
            // wave 0 polls all 64 flags at once (ballot-reduce)
            if (wave == 0) {
                uint32 v;
                do {
                    v = __hip_atomic_load(&flags[lane * 16],
                                          __ATOMIC_RELAXED, __HIP_MEMORY_SCOPE_AGENT);
                } while (__ballot(v >= (uint32)(t + 1)) != ~0ull);
            }
            if (tid == 0) __threadfence();   // acquire: invalidate, see fresh h
            __syncthreads();
        }
    }
}

// ---------------------------------------------------------------------------
// Fallback (ws too small for xproj): R4 kernel, verbatim.
// ---------------------------------------------------------------------------
__launch_bounds__(512, 2)
__global__ void lstm_scan_fused(const float* __restrict__ x,
                                const float* __restrict__ wih,
                                const float* __restrict__ whh,
                                const float* __restrict__ bias,
                                ushort_t* __restrict__ h0buf,
                                ushort_t* __restrict__ h1buf,
                                float* __restrict__ out,
                                uint32* __restrict__ ctr)
{
    const int tid  = threadIdx.x;
    const int bid  = blockIdx.x;
    const int wave = tid >> 6, lane = tid & 63, l16 = lane & 15, quad = lane >> 4;
    const int g     = wave & 3;
    const int khalf = wave >> 2;
    const int unit0 = bid * 16;
    const int col0  = g * 1024 + unit0 + l16;
    const int kbase = khalf * 512;

    __shared__ ushort_t xs[32 * 1024];
    __shared__ float gA[4 * 32 * 17];
    __shared__ float gB[4 * 32 * 17];

    short8 wif[16], whf[16];
#pragma unroll
    for (int kk = 0; kk < 16; kk++) {
        short8 vi, vh;
#pragma unroll
        for (int j = 0; j < 8; j++) {
            const size_t k = (size_t)(kbase + kk * 32 + quad * 8 + j);
            vi[j] = (short)f2b_rne(wih[k * G4_ + col0]);
            vh[j] = (short)f2b_rne(whh[k * G4_ + col0]);
        }
        wif[kk] = vi;
        whf[kk] = vh;
    }
    const float bcol = (khalf == 0) ? bias[col0] : 0.f;

    const int eb = tid >> 4, ej = tid & 15;
    const int hwoff = (bid >> 1) * 1024 + eb * 32 + 16 * (bid & 1) + ej;
    float cst = 0.f;

    floatx4 a0a, a0b, a1a, a1b;

    {
        const int sb = tid >> 4, sc = tid & 15;
        const float* xrow = x + ((size_t)sb * T_ + 0) * H_ + sc * 64;
#pragma unroll
        for (int q = 0; q < 8; q++) {
            const uint4 u0 = *(const uint4*)(xrow + q * 8);
            const uint4 u1 = *(const uint4*)(xrow + q * 8 + 4);
            uint4 p;
            p.x = __builtin_amdgcn_perm(u0.y, u0.x, 0x07060302u);
            p.y = __builtin_amdgcn_perm(u0.w, u0.z, 0x07060302u);
            p.z = __builtin_amdgcn_perm(u1.y, u1.x, 0x07060302u);
            p.w = __builtin_amdgcn_perm(u1.w, u1.z, 0x07060302u);
            const int k = sc * 64 + q * 8;
            *(uint4*)&xs[(k >> 5) * 1024 + sb * 32 + (k & 31)] = p;
        }
    }
    __syncthreads();
    a0a = (floatx4){bcol, bcol, bcol, bcol};
    a1a = a0a;
    a0b = (floatx4){0.f, 0.f, 0.f, 0.f};
    a1b = a0b;
#pragma unroll
    for (int kk = 0; kk < 16; kk++) {
        const ushort_t* ps = &xs[(khalf * 16 + kk) * 1024 + quad * 8];
        const short8 a0 = *(const short8*)(ps + l16 * 32);
        const short8 a1 = *(const short8*)(ps + (16 + l16) * 32);
        if (kk & 1) {
            a0b = __builtin_amdgcn_mfma_f32_16x16x32_bf16(a0, wif[kk], a0b, 0, 0, 0);
            a1b = __builtin_amdgcn_mfma_f32_16x16x32_bf16(a1, wif[kk], a1b, 0, 0, 0);
        } else {
            a0a = __builtin_amdgcn_mfma_f32_16x16x32_bf16(a0, wif[kk], a0a, 0, 0, 0);
            a1a = __builtin_amdgcn_mfma_f32_16x16x32_bf16(a1, wif[kk], a1a, 0, 0, 0);
        }
    }

    for (int t = 0; t < 512; t++) {
        const ushort_t* hr = (t & 1) ? h1buf : h0buf;
        ushort_t*       hw = (t & 1) ? h0buf : h1buf;

#pragma unroll
        for (int kk = 0; kk < 16; kk++) {
            const ushort_t* pa = hr + (khalf * 16 + kk) * 1024 + quad * 8;
            const short8 a0 = *(const short8*)(pa + l16 * 32);
            const short8 a1 = *(const short8*)(pa + (16 + l16) * 32);
            if (kk & 1) {
                a0b = __builtin_amdgcn_mfma_f32_16x16x32_bf16(a0, whf[kk], a0b, 0, 0, 0);
                a1b = __builtin_amdgcn_mfma_f32_16x16x32_bf16(a1, whf[kk], a1b, 0, 0, 0);
            } else {
                a0a = __builtin_amdgcn_mfma_f32_16x16x32_bf16(a0, whf[kk], a0a, 0, 0, 0);
                a1a = __builtin_amdgcn_mfma_f32_16x16x32_bf16(a1, whf[kk], a1a, 0, 0, 0);
            }
        }
        const floatx4 s0 = a0a + a0b;
        const floatx4 s1 = a1a + a1b;
        float* gd = khalf ? gB : gA;
#pragma unroll
        for (int rr = 0; rr < 4; rr++) {
            gd[(g * 32 + quad * 4 + rr) * 17 + l16]      = s0[rr];
            gd[(g * 32 + 16 + quad * 4 + rr) * 17 + l16] = s1[rr];
        }
        __syncthreads();

        {
            const float gi = gA[(0 * 32 + eb) * 17 + ej] + gB[(0 * 32 + eb) * 17 + ej];
            const float gf = gA[(1 * 32 + eb) * 17 + ej] + gB[(1 * 32 + eb) * 17 + ej];
            const float gg = gA[(2 * 32 + eb) * 17 + ej] + gB[(2 * 32 + eb) * 17 + ej];
            const float go = gA[(3 * 32 + eb) * 17 + ej] + gB[(3 * 32 + eb) * 17 + ej];
            const float iv = sigm(gi);
            const float fv = sigm(gf);
            const float gv = tanh_(gg);
            const float ov = sigm(go);
            const float c = fv * cst + iv * gv;
            cst = c;
            const float h = ov * tanh_(c);
            hw[hwoff] = f2b_rne(h);
            out[((size_t)eb * T_ + t) * H_ + unit0 + ej] = h;
            if (t == 511) {
                out[HSEQ_ + eb * H_ + unit0 + ej] = h;
                out[HSEQ_ + B_ * H_ + eb * H_ + unit0 + ej] = cst;
            }
        }
        __syncthreads();

        if (t < 511) {
            if (tid == 0) {
                __threadfence();
                __hip_atomic_fetch_add(ctr, 1u, __ATOMIC_RELAXED, __HIP_MEMORY_SCOPE_AGENT);
            }
            {
                const int sb = tid >> 4, sc = tid & 15;
                const float* xrow = x + ((size_t)sb * T_ + (t + 1)) * H_ + sc * 64;
#pragma unroll
                for (int q = 0; q < 8; q++) {
                    const uint4 u0 = *(const uint4*)(xrow + q * 8);
                    const uint4 u1 = *(const uint4*)(xrow + q * 8 + 4);
                    uint4 p;
                    p.x = __builtin_amdgcn_perm(u0.y, u0.x, 0x07060302u);
                    p.y = __builtin_amdgcn_perm(u0.w, u0.z, 0x07060302u);
                    p.z = __builtin_amdgcn_perm(u1.y, u1.x, 0x07060302u);
                    p.w = __builtin_amdgcn_perm(u1.w, u1.z, 0x07060302u);
                    const int k = sc * 64 + q * 8;
                    *(uint4*)&xs[(k >> 5) * 1024 + sb * 32 + (k & 31)] = p;
                }
            }
            __syncthreads();
            a0a = (floatx4){bcol, bcol, bcol, bcol};
            a1a = a0a;
            a0b = (floatx4){0.f, 0.f, 0.f, 0.f};
            a1b = a0b;
#pragma unroll
            for (int kk = 0; kk < 16; kk++) {
                const ushort_t* ps = &xs[(khalf * 16 + kk) * 1024 + quad * 8];
                const short8 a0 = *(const short8*)(ps + l16 * 32);
                const short8 a1 = *(const short8*)(ps + (16 + l16) * 32);
                if (kk & 1) {
                    a0b = __builtin_amdgcn_mfma_f32_16x16x32_bf16(a0, wif[kk], a0b, 0, 0, 0);
                    a1b = __builtin_amdgcn_mfma_f32_16x16x32_bf16(a1, wif[kk], a1b, 0, 0, 0);
                } else {
                    a0a = __builtin_amdgcn_mfma_f32_16x16x32_bf16(a0, wif[kk], a0a, 0, 0, 0);
                    a1a = __builtin_amdgcn_mfma_f32_16x16x32_bf16(a1, wif[kk], a1a, 0, 0, 0);
                }
            }
            if (tid == 0) {
                const uint32 target = (uint32)NBLK * (uint32)(t + 1);
                while (__hip_atomic_load(ctr, __ATOMIC_RELAXED, __HIP_MEMORY_SCOPE_AGENT) < target) {
                    __builtin_amdgcn_s_sleep(1);
                }
                __threadfence();
            }
            __syncthreads();
        }
    }
}

// ---------------------------------------------------------------------------
extern "C" void kernel_launch(void* const* d_in, const int* in_sizes, int n_in,
                              void* d_out, int out_size, void* d_ws, size_t ws_size,
                              hipStream_t stream)
{
    const float* x    = (const float*)d_in[0];  // [32,512,1024] f32
    const float* wih  = (const float*)d_in[1];  // [1024,4096] f32
    const float* whh  = (const float*)d_in[2];  // [1024,4096] f32
    const float* bias = (const float*)d_in[3];  // [4096] f32
    float* out = (float*)d_out;
    char* ws = (char*)d_ws;

    if (ws_size >= WS_NEED) {
        ushort_t* xproj = (ushort_t*)(ws + XPROJ_OFF);
        ushort_t* wtih  = (ushort_t*)(ws + WTIH_OFF);
        ushort_t* wthh  = (ushort_t*)(ws + WTHH_OFF);
        ushort_t* h0    = (ushort_t*)(ws + H0X_OFF);
        ushort_t* h1    = (ushort_t*)(ws + H1X_OFF);
        uint32*   flags = (uint32*)(ws + FLAGS_OFF);

        hipMemsetAsync(ws + H0X_OFF, 0, 2 * 65536 + 4096, stream);
        hipLaunchKernelGGL(transpose_cvt, dim3(2048), dim3(256), 0, stream, wih, wtih);
        hipLaunchKernelGGL(transpose_cvt, dim3(2048), dim3(256), 0, stream, whh, wthh);
        hipLaunchKernelGGL(gemm_xproj, dim3(32, 128), dim3(256), 0, stream,
                           x, wtih, bias, xproj);
        hipLaunchKernelGGL(lstm_scan_xp, dim3(NBLK), dim3(512), 0, stream,
                           xproj, wthh, h0, h1, out, flags);
    } else {
        ushort_t* h0  = (ushort_t*)(ws + H0_OFF);
        ushort_t* h1  = (ushort_t*)(ws + H1_OFF);
        uint32*   ctr = (uint32*)(ws + CTR_OFF);

        hipMemsetAsync(ws, 0, 131072 + 256, stream);
        hipLaunchKernelGGL(lstm_scan_fused, dim3(NBLK), dim3(512), 0, stream,
                           x, wih, whh, bias, h0, h1, out, ctr);
    }
}